// Round 8
// baseline (179.147 us; speedup 1.0000x reference)
//
#include <hip/hip_runtime.h>
#include <math.h>

#define M_ 64
#define N_ 2048
#define D_ 256
#define J_ 384
#define C2N 64    // chunks of 32 rows
#define CN2 32

typedef _Float16 half8 __attribute__((ext_vector_type(8)));
typedef float f32x4 __attribute__((ext_vector_type(4)));

// ---- ws byte offsets ----
#define OFF_F16   0u        // [64 l][384 j] f16 CDF table : 49152
#define OFF_LG8   49152u    // [49] f32 lgamma(8i+1) : 256 (padded)
#define OFF_INV   49408u    // [384] f32 1/(i+1) : 1536
#define OFF_SQX   50944u    // [64] f32 : 256
#define OFF_PRED  51200u    // [128] f32 : 512
#define OFF_CHUNK 51712u    // [64 m][64 c2][64 l] f64 : 2097152
#define OFF_PSUM  2148864u  // [64*2048][64] f32 : 33554432 (~35.7 MB total)

// blocks 0..47: F16[l][jg*8 .. jg*8+7] from independent gammainc starts
// block 48: housekeeping (sqX, lg8, invt, pred)
__global__ __launch_bounds__(64)
void k_tab(const float* __restrict__ buckets, const float* __restrict__ Xg,
           char* __restrict__ ws) {
    _Float16* F16 = (_Float16*)(ws + OFF_F16);
    float* lg8  = (float*)(ws + OFF_LG8);
    float* invt = (float*)(ws + OFF_INV);
    float* sqX  = (float*)(ws + OFF_SQX);
    float* pred = (float*)(ws + OFF_PRED);
    int jg = blockIdx.x, l = threadIdx.x;

    if (jg < 48) {
        const double x = (double)buckets[l] * 0.125;   // 0.5*bucket/SIGMA2
        const double a = 128.0 + 8.0 * (double)jg;     // 0.5*D + 8*jg
        double gln = lgamma(a);
        double q;                                      // Q(a,x) upper regularized
        if (x < a + 1.0) {
            double ap = a, sum = 1.0 / a, del = sum;
            for (int it = 0; it < 2000; ++it) {
                ap += 1.0; del *= x / ap; sum += del;
                if (fabs(del) < fabs(sum) * 1e-16) break;
            }
            q = 1.0 - sum * exp(-x + a * log(x) - gln);
        } else {
            double b = x + 1.0 - a, cc = 1e300, d = 1.0 / b, h = d;
            for (int i = 1; i <= 2000; ++i) {
                double an = -(double)i * ((double)i - a);
                b += 2.0;
                d = an * d + b; if (fabs(d) < 1e-300) d = 1e-300;
                cc = b + an / cc; if (fabs(cc) < 1e-300) cc = 1e-300;
                d = 1.0 / d;
                double delc = d * cc; h *= delc;
                if (fabs(delc - 1.0) < 1e-16) break;
            }
            q = exp(-x + a * log(x) - gln) * h;
        }
        double tt = exp(a * log(x) - x - lgamma(a + 1.0));
        for (int jj = 0; jj < 8; ++jj) {
            double F = 1.0 - q; if (F < 0.0) F = 0.0;
            F16[l * J_ + (jg << 3) + jj] = (_Float16)F;
            q += tt; if (q > 1.0) q = 1.0;
            tt *= x / (a + (double)jj + 1.0);
        }
    } else {
        const float4* xr = (const float4*)(Xg + l * D_);
        float s0 = 0, s1 = 0, s2 = 0, s3 = 0;
        for (int k = 0; k < D_ / 4; ++k) {
            float4 v = xr[k];
            s0 = fmaf(v.x, v.x, s0); s1 = fmaf(v.y, v.y, s1);
            s2 = fmaf(v.z, v.z, s2); s3 = fmaf(v.w, v.w, s3);
        }
        sqX[l] = (s0 + s1) + (s2 + s3);
        if (l < 49) lg8[l] = (float)lgamma(8.0 * (double)l + 1.0);
        for (int i = l; i < J_; i += 64) invt[i] = 1.0f / (float)(i + 1);
        pred[2 * l] = 0.f; pred[2 * l + 1] = 0.f;
    }
}

// Fused: dist prologue + R = sum_j w_j F16[l][j] via f16 MFMA (+ j-window skip)
// + per-32-row chunk log-sums. block = 128 thr = 2 waves; tile 64 n x 64 l.
__global__ __launch_bounds__(128)
void k_fused(const float* __restrict__ Xg, const float* __restrict__ TXg,
             char* __restrict__ ws) {
    const _Float16* F16 = (const _Float16*)(ws + OFF_F16);
    const float* lg8    = (const float*)(ws + OFF_LG8);
    const float* invt   = (const float*)(ws + OFF_INV);
    const float* sqX    = (const float*)(ws + OFF_SQX);
    float* psum         = (float*)(ws + OFF_PSUM);
    double* chunk       = (double*)(ws + OFF_CHUNK);

    __shared__ float  s_dist[64];
    __shared__ double s_part[2][64];

    int bid = blockIdx.x;            // 2048 = m*32 + c
    int m = bid >> 5, c = bid & 31;
    int n0 = c << 6;
    int t = threadIdx.x;

    // ---- prologue: 64 distances (2 threads per row) ----
    {
        int nloc = t >> 1, half = t & 1;
        const float4* T4 = (const float4*)(TXg + (size_t)(n0 + nloc) * D_ + (half << 7));
        const float4* X4 = (const float4*)(Xg + m * D_ + (half << 7));
        float4 dd{0,0,0,0}, ss{0,0,0,0};
#pragma unroll 8
        for (int k = 0; k < 32; ++k) {
            float4 tv = T4[k], xv = X4[k];
            dd.x = fmaf(xv.x, tv.x, dd.x); dd.y = fmaf(xv.y, tv.y, dd.y);
            dd.z = fmaf(xv.z, tv.z, dd.z); dd.w = fmaf(xv.w, tv.w, dd.w);
            ss.x = fmaf(tv.x, tv.x, ss.x); ss.y = fmaf(tv.y, tv.y, ss.y);
            ss.z = fmaf(tv.z, tv.z, ss.z); ss.w = fmaf(tv.w, tv.w, ss.w);
        }
        float dot = (dd.x + dd.y) + (dd.z + dd.w);
        float st  = (ss.x + ss.y) + (ss.z + ss.w);
        dot += __shfl_xor(dot, 1);
        st  += __shfl_xor(st, 1);
        if (half == 0)
            s_dist[nloc] = fmaxf(sqX[m] + st - 2.f * dot, 0.f);
    }
    __syncthreads();

    const int w = t >> 6, l = t & 63;
    const int col = l & 15, g = l >> 4;
    const int rbase = n0 + (w << 5);

    float la0 = s_dist[(w << 5) + col]      * 0.125f;   // lambda = dist/8
    float la1 = s_dist[(w << 5) + 16 + col] * 0.125f;
    float ll0 = __logf(la0), ll1 = __logf(la1);

    f32x4 acc00 = {0,0,0,0}, acc01 = {0,0,0,0}, acc02 = {0,0,0,0}, acc03 = {0,0,0,0};
    f32x4 acc10 = {0,0,0,0}, acc11 = {0,0,0,0}, acc12 = {0,0,0,0}, acc13 = {0,0,0,0};

    for (int s = 0; s < 12; ++s) {
        // skip test at exact interval endpoints j=32s, j=32s+32 (lg8 is exact there).
        // logw concave; if peak inside, nearer endpoint >= peak - 32^2/(2*lam) > -35.
        float jb0f = (float)(s << 5);
        float jb1f = jb0f + 32.f;
        float lgLo = lg8[s << 2], lgHi = lg8[(s << 2) + 4];
        float e00 = fmaf(jb0f, ll0, -la0) - lgLo;
        float e01 = fmaf(jb1f, ll0, -la0) - lgHi;
        float e10 = fmaf(jb0f, ll1, -la1) - lgLo;
        float e11 = fmaf(jb1f, ll1, -la1) - lgHi;
        float mx = fmaxf(fmaxf(e00, e01), fmaxf(e10, e11));
        if (!__any(mx > -35.f)) continue;   // all weights < e^-35: negligible

        int jb = (s << 5) + (g << 3);
        float jbf = (float)jb;
        half8 b0 = *(const half8*)(F16 + (size_t)(col     ) * J_ + jb);
        half8 b1 = *(const half8*)(F16 + (size_t)(col + 16) * J_ + jb);
        half8 b2 = *(const half8*)(F16 + (size_t)(col + 32) * J_ + jb);
        half8 b3 = *(const half8*)(F16 + (size_t)(col + 48) * J_ + jb);
        float lgv = lg8[(s << 2) + g];
        float4 iv0 = *(const float4*)(invt + jb);
        float4 iv1 = *(const float4*)(invt + jb + 4);
        {
            float wv = __expf(fmaf(jbf, ll0, -la0 - lgv));
            half8 a;
            a[0] = (_Float16)wv;
            wv *= la0 * iv0.x; a[1] = (_Float16)wv;
            wv *= la0 * iv0.y; a[2] = (_Float16)wv;
            wv *= la0 * iv0.z; a[3] = (_Float16)wv;
            wv *= la0 * iv0.w; a[4] = (_Float16)wv;
            wv *= la0 * iv1.x; a[5] = (_Float16)wv;
            wv *= la0 * iv1.y; a[6] = (_Float16)wv;
            wv *= la0 * iv1.z; a[7] = (_Float16)wv;
            acc00 = __builtin_amdgcn_mfma_f32_16x16x32_f16(a, b0, acc00, 0, 0, 0);
            acc01 = __builtin_amdgcn_mfma_f32_16x16x32_f16(a, b1, acc01, 0, 0, 0);
            acc02 = __builtin_amdgcn_mfma_f32_16x16x32_f16(a, b2, acc02, 0, 0, 0);
            acc03 = __builtin_amdgcn_mfma_f32_16x16x32_f16(a, b3, acc03, 0, 0, 0);
        }
        {
            float wv = __expf(fmaf(jbf, ll1, -la1 - lgv));
            half8 a;
            a[0] = (_Float16)wv;
            wv *= la1 * iv0.x; a[1] = (_Float16)wv;
            wv *= la1 * iv0.y; a[2] = (_Float16)wv;
            wv *= la1 * iv0.z; a[3] = (_Float16)wv;
            wv *= la1 * iv0.w; a[4] = (_Float16)wv;
            wv *= la1 * iv1.x; a[5] = (_Float16)wv;
            wv *= la1 * iv1.y; a[6] = (_Float16)wv;
            wv *= la1 * iv1.z; a[7] = (_Float16)wv;
            acc10 = __builtin_amdgcn_mfma_f32_16x16x32_f16(a, b0, acc10, 0, 0, 0);
            acc11 = __builtin_amdgcn_mfma_f32_16x16x32_f16(a, b1, acc11, 0, 0, 0);
            acc12 = __builtin_amdgcn_mfma_f32_16x16x32_f16(a, b2, acc12, 0, 0, 0);
            acc13 = __builtin_amdgcn_mfma_f32_16x16x32_f16(a, b3, acc13, 0, 0, 0);
        }
    }

    // ---- epilogue: psi = 1-R, store, per-32-row f64 log-sums ----
    double lsum0 = 0.0, lsum1 = 0.0, lsum2 = 0.0, lsum3 = 0.0;
    float* pbase = psum + (((size_t)(m << 11) + rbase) << 6);
#define EPI(ACC, SP, TI, LS)                                                    \
    {                                                                           \
        _Pragma("unroll")                                                       \
        for (int r = 0; r < 4; ++r) {                                           \
            float ps = 1.f - (ACC)[r];                                          \
            int row = (SP) * 16 + g * 4 + r;                                    \
            pbase[((size_t)row << 6) + (TI) * 16 + col] = ps;                   \
            LS += (double)__logf(fmaxf(ps, 1e-30f));                            \
        }                                                                       \
    }
    EPI(acc00, 0, 0, lsum0) EPI(acc01, 0, 1, lsum1) EPI(acc02, 0, 2, lsum2) EPI(acc03, 0, 3, lsum3)
    EPI(acc10, 1, 0, lsum0) EPI(acc11, 1, 1, lsum1) EPI(acc12, 1, 2, lsum2) EPI(acc13, 1, 3, lsum3)
#undef EPI
    lsum0 += __shfl_xor(lsum0, 16); lsum0 += __shfl_xor(lsum0, 32);
    lsum1 += __shfl_xor(lsum1, 16); lsum1 += __shfl_xor(lsum1, 32);
    lsum2 += __shfl_xor(lsum2, 16); lsum2 += __shfl_xor(lsum2, 32);
    lsum3 += __shfl_xor(lsum3, 16); lsum3 += __shfl_xor(lsum3, 32);
    if (g == 0) {
        s_part[w][col]      = lsum0;
        s_part[w][16 + col] = lsum1;
        s_part[w][32 + col] = lsum2;
        s_part[w][48 + col] = lsum3;
    }
    __syncthreads();
    // chunk granularity 32 rows: c2 = 2c + w2 ; both waves' parts written directly
    {
        int w2 = t >> 6, l2 = t & 63;
        chunk[(((m << 6) + (c << 1) + w2) << 6) + l2] = s_part[w2][l2];
    }
}

// scan: block = (m, 4 chunks of 32 rows), 4 waves; wave w -> chunk c2 = cg*4+w
__global__ __launch_bounds__(256)
void k_scan(const int* __restrict__ ty, char* __restrict__ ws) {
    const float* psum   = (const float*)(ws + OFF_PSUM);
    const double* chunk = (const double*)(ws + OFF_CHUNK);
    float* pred         = (float*)(ws + OFF_PRED);
    int b = blockIdx.x;              // 1024 = m*16 + cg
    int m = b >> 4, cg = b & 15;
    int t = threadIdx.x;
    int w = t >> 6, l = t & 63;
    int c2 = (cg << 2) + w;

    // prefix over 32-row chunks (L1/L2-hot: same 32 KB per m, broadcast)
    const double* ch = chunk + ((size_t)(m << 6) << 6) + l;
    double cum = 0.0, T = 0.0;
    for (int k = 0; k < C2N; ++k) {
        double v = ch[(size_t)k << 6];
        T += v;
        if (k < c2) cum += v;
    }

    const float* P = psum + (((size_t)(m << 11) + (c2 << 5)) << 6);
    int nb = c2 << 5;
    float a0 = 0.f, a1 = 0.f;
    for (int i = 0; i < CN2; ++i) {
        float pv = P[((size_t)i << 6) + l];
        float lv = __logf(fmaxf(pv, 1e-30f));
        double nbr = __shfl_down(cum, 1);           // cum[n-1, l+1]
        float pvn  = __shfl_down(pv, 1);            // psum[n, l+1]
        double cin = cum + (double)lv;              // cum[n, l]
        int n = nb + i;
        double t1 = (n == 0) ? 0.0 : ((l == 63) ? -999999.0 : nbr);
        float e = (float)(t1 + (T - cin));
        float pm = (l == 63) ? pv : (pv - pvn);
        float contrib = pm * __expf(e);
        int y = ty[n];                              // wave-uniform
        a0 += (y == 0) ? contrib : 0.f;
        a1 += (y == 1) ? contrib : 0.f;
        cum = cin;
    }
#pragma unroll
    for (int o = 32; o > 0; o >>= 1) {
        a0 += __shfl_down(a0, o);
        a1 += __shfl_down(a1, o);
    }
    if (l == 0) {
        atomicAdd(&pred[m * 2 + 0], a0);
        atomicAdd(&pred[m * 2 + 1], a1);
    }
}

__global__ __launch_bounds__(64)
void k_norm(char* __restrict__ ws, float* __restrict__ out) {
    const float* pred = (const float*)(ws + OFF_PRED);
    int m = threadIdx.x;
    float a = pred[2 * m], b = pred[2 * m + 1];
    float s = a + b;
    out[2 * m]     = a / s;
    out[2 * m + 1] = b / s;
}

extern "C" void kernel_launch(void* const* d_in, const int* in_sizes, int n_in,
                              void* d_out, int out_size, void* d_ws, size_t ws_size,
                              hipStream_t stream) {
    const float* X       = (const float*)d_in[0];
    const float* train_X = (const float*)d_in[1];
    const float* buckets = (const float*)d_in[2];
    const int*   train_y = (const int*)d_in[3];
    float* out = (float*)d_out;
    char*  ws  = (char*)d_ws;

    k_tab<<<49, 64, 0, stream>>>(buckets, X, ws);
    k_fused<<<M_ * 32, 128, 0, stream>>>(X, train_X, ws);
    k_scan<<<M_ * 16, 256, 0, stream>>>(train_y, ws);
    k_norm<<<1, 64, 0, stream>>>(ws, out);
}